// Round 2
// baseline (377.091 us; speedup 1.0000x reference)
//
#include <hip/hip_runtime.h>
#include <stdint.h>

// ---------------------------------------------------------------------------
// Problem constants (from reference)
// ---------------------------------------------------------------------------
#define C_RMIN 100000.0f
#define C_RMAX 10000000.0f
#define C_CMIN 1e-07f
#define C_CMAX 1e-04f
#define C_DT   0.1f
#define C_EPS  0.05f
#define C_COUP 0.2f

// ---------------------------------------------------------------------------
// Threefry-2x32 (exact JAX semantics). Host+device.
// ---------------------------------------------------------------------------
__host__ __device__ inline void tf2x32(uint32_t k0, uint32_t k1,
                                       uint32_t& x0, uint32_t& x1) {
  uint32_t ks2 = k0 ^ k1 ^ 0x1BD11BDAu;
  uint32_t a = x0 + k0, b = x1 + k1;
#define TFR(r) a += b; b = (b << (r)) | (b >> (32 - (r))); b ^= a;
  TFR(13) TFR(15) TFR(26) TFR(6)
  a += k1;  b += ks2 + 1u;
  TFR(17) TFR(29) TFR(16) TFR(24)
  a += ks2; b += k0 + 2u;
  TFR(13) TFR(15) TFR(26) TFR(6)
  a += k0;  b += k1 + 3u;
  TFR(17) TFR(29) TFR(16) TFR(24)
  a += k1;  b += ks2 + 4u;
  TFR(13) TFR(15) TFR(26) TFR(6)
  a += ks2; b += k0 + 5u;
#undef TFR
  x0 = a; x1 = b;
}

// jax.random.uniform element e, PARTITIONABLE threefry (jax>=0.5 default):
// one block per element, counter = (hi(e)=0, lo(e)=e), bits = out0 ^ out1.
__device__ inline float unif01(uint32_t k0, uint32_t k1, uint32_t e) {
  uint32_t x0 = 0u, x1 = e;
  tf2x32(k0, k1, x0, x1);
  uint32_t bits = x0 ^ x1;
  return __uint_as_float((bits >> 9) | 0x3F800000u) - 1.0f;
}

__device__ inline float theta_eff(float t) {
  t = fminf(fmaxf(t, -10.0f), 10.0f);
  return (fabsf(t) < 0.01f) ? 0.0f : t;
}

__device__ inline float sigmoidf(float x) { return 1.0f / (1.0f + expf(-x)); }

__device__ inline float noise_mul(float u) { return (u * 2.0f - 1.0f) * C_EPS + 1.0f; }

// ---------------------------------------------------------------------------
// W1: effective weights for pmac1.  S1eff[n][m][o], m in 0..32 (32 = bias row).
// noise shape (4,34,32): e=(n*34+m)*32+o.
// ---------------------------------------------------------------------------
__global__ void w1_kernel(const float* __restrict__ theta1, float* __restrict__ S1eff,
                          uint32_t ka, uint32_t kb) {
  int n = blockIdx.x;      // 0..3
  int o = threadIdx.x;     // 0..31
  float tn[34];
  float den = 0.0f;
  for (int m = 0; m < 34; ++m) {
    float t = theta_eff(theta1[m * 32 + o]);
    float u = unif01(ka, kb, (uint32_t)((n * 34 + m) * 32 + o));
    float v = t * noise_mul(u);
    tn[m] = v;
    den += fabsf(v);
  }
  den += 1e-10f;
  for (int m = 0; m < 33; ++m)
    S1eff[(n * 33 + m) * 32 + o] = tn[m] / den;
}

// ---------------------------------------------------------------------------
// W2a: denominators for pmac2.  denom2[n][o] = sum_{j=0..1057} |thn2| + 1e-10
// noise shape (4,1058,32): e=(n*1058+j)*32+o.
// ---------------------------------------------------------------------------
__global__ void w2a_kernel(const float* __restrict__ theta2, float* __restrict__ denom2,
                           uint32_t ka, uint32_t kb) {
  int n = blockIdx.x;                 // 0..3
  int o = threadIdx.x & 31;
  int jc = threadIdx.x >> 5;          // 0..7
  float part = 0.0f;
  for (int j = jc; j < 1058; j += 8) {
    float t = theta_eff(theta2[j * 32 + o]);
    float u = unif01(ka, kb, (uint32_t)((n * 1058 + j) * 32 + o));
    part += fabsf(t * noise_mul(u));
  }
  __shared__ float red[256];
  red[jc * 32 + o] = part;
  __syncthreads();
  if (jc == 0) {
    float s = 0.0f;
    for (int q = 0; q < 8; ++q) s += red[q * 32 + o];
    denom2[n * 32 + o] = s + 1e-10f;
  }
}

// ---------------------------------------------------------------------------
// W2b: S2eff[n][j][o] = thn2/denom2, j in 0..1056 (1056 = bias row).
// ---------------------------------------------------------------------------
__global__ void w2b_kernel(const float* __restrict__ theta2, const float* __restrict__ denom2,
                           float* __restrict__ S2eff, uint32_t ka, uint32_t kb) {
  int idx = blockIdx.x * 256 + threadIdx.x;
  if (idx >= 4 * 1057 * 32) return;
  int o = idx & 31;
  int r = idx >> 5;
  int j = r % 1057;
  int n = r / 1057;
  float t = theta_eff(theta2[j * 32 + o]);
  float u = unif01(ka, kb, (uint32_t)((n * 1058 + j) * 32 + o));
  S2eff[idx] = t * noise_mul(u) / denom2[n * 32 + o];
}

// ---------------------------------------------------------------------------
// P1: first pmac.  a1[n][b][o][t] = 0.05+0.5*tanh(3*(z-0.3)),
//     z = sum_m x[n,b,m,t]*S1[n,m,o] + S1[n,32,o].
// Block per (n,b), thread per t.
// ---------------------------------------------------------------------------
__global__ __launch_bounds__(256) void p1_kernel(const float* __restrict__ x,
                                                 const float* __restrict__ S1eff,
                                                 float* __restrict__ a1) {
  int n = blockIdx.x >> 5, b = blockIdx.x & 31;
  int t = threadIdx.x;
  __shared__ float xs[32][256];
  const float* xp = x + (size_t)((n * 32 + b) * 32) * 256;
  for (int m = 0; m < 32; ++m) xs[m][t] = xp[m * 256 + t];
  __syncthreads();
  const float* S = S1eff + n * 33 * 32;
  float* ap = a1 + (size_t)((n * 32 + b) * 32) * 256;
  for (int o = 0; o < 32; ++o) {
    float z = S[32 * 32 + o];
#pragma unroll
    for (int m = 0; m < 32; ++m) z += xs[m][t] * S[m * 32 + o];
    ap[o * 256 + t] = 0.05f + 0.5f * tanhf((z - 0.3f) * 3.0f);
  }
}

// ---------------------------------------------------------------------------
// B: beta arrays for both cascades.  beta[c][n][t][k] layout [n*256+t][k].
// nR/nC/mu shape (256,1024,4,1): e=(t*1024+k)*4+n.
// ---------------------------------------------------------------------------
__global__ void beta_kernel(const float* __restrict__ Rlf, const float* __restrict__ Clf,
                            float* __restrict__ beta1, float* __restrict__ beta2,
                            uint32_t kR1a, uint32_t kR1b, uint32_t kC1a, uint32_t kC1b,
                            uint32_t kM1a, uint32_t kM1b,
                            uint32_t kR2a, uint32_t kR2b, uint32_t kC2a, uint32_t kC2b,
                            uint32_t kM2a, uint32_t kM2b) {
  int idx = blockIdx.x * 256 + threadIdx.x;   // 0 .. 2*1048576-1
  int casc = idx >> 20;
  int r = idx & 1048575;
  int n = r >> 18;
  int t = (r >> 10) & 255;
  int k = r & 1023;
  uint32_t e = (uint32_t)((t * 1024 + k) * 4 + n);
  uint32_t ra = casc ? kR2a : kR1a, rb = casc ? kR2b : kR1b;
  uint32_t ca = casc ? kC2a : kC1a, cb = casc ? kC2b : kC1b;
  uint32_t ma = casc ? kM2a : kM1a, mb = casc ? kM2b : kM1b;
  float R_ = Rlf[k * 2 + casc];
  float C_ = Clf[k * 2 + casc];
  float Rt = sigmoidf(R_) * (C_RMAX - C_RMIN) + C_RMIN;
  float Ct = sigmoidf(C_) * (C_CMAX - C_CMIN) + C_CMIN;
  float nR = noise_mul(unif01(ra, rb, e));
  float nC = noise_mul(unif01(ca, cb, e));
  float mu = unif01(ma, mb, e) * C_COUP + 1.0f;
  float rc = mu * (Rt * nR) * (Ct * nC);
  float bt = rc / (rc + C_DT);
  float* outp = casc ? beta2 : beta1;
  outp[(n * 256 + t) * 1024 + k] = bt;
}

// ---------------------------------------------------------------------------
// FK: fused dual filter cascade + final pmac.
// Block per (n,b): 1024 threads, thread tid owns filter k=tid.
// Thread role for reduction: (q = tid>>5, o = tid&31); chunk q == channel c.
// s0_1: uniform(k01,(1024,4,32)) e=(k*4+n)*32+b; s0_2 with k02.
// Output out[n][b][o][t].
// ---------------------------------------------------------------------------
__global__ __launch_bounds__(1024) void fk_kernel(const float* __restrict__ a1,
                                                  const float* __restrict__ S2eff,
                                                  const float* __restrict__ beta1,
                                                  const float* __restrict__ beta2,
                                                  float* __restrict__ out,
                                                  uint32_t k01a, uint32_t k01b,
                                                  uint32_t k02a, uint32_t k02b) {
  int n = blockIdx.x >> 5, b = blockIdx.x & 31;
  int tid = threadIdx.x;
  int o = tid & 31, q = tid >> 5;

  __shared__ float xz[32 * 257];   // [o][t], padded
  __shared__ float y_lds[1024];
  __shared__ float part[1024];     // [q][o]

  const float* S2n = S2eff + (size_t)n * 1057 * 32;

  // per-thread filter-output weights: w for channels j = q*33+1+i (filters k=q*32+i)
  float wreg[32];
#pragma unroll
  for (int i = 0; i < 32; ++i) wreg[i] = S2n[(q * 33 + 1 + i) * 32 + o];

  // filter states (k = tid)
  int k = tid;
  uint32_t e0 = (uint32_t)((k * 4 + n) * 32 + b);
  float s1 = unif01(k01a, k01b, e0);
  float s2 = unif01(k02a, k02b, e0);

  // xz[o][t] = bias + sum_c a1[n,b,c,t] * S2[n, c*33, o]
  const float* a1nb = a1 + (size_t)((n * 32 + b) * 32) * 256;
  {
    float bias = S2n[1056 * 32 + o];
    for (int it = 0; it < 8; ++it) {
      int t = q * 8 + it;
      float z = bias;
#pragma unroll
      for (int c = 0; c < 32; ++c) z += a1nb[c * 256 + t] * S2n[(c * 33) * 32 + o];
      xz[o * 257 + t] = z;
    }
  }
  __syncthreads();

  const int cc = k >> 5;  // input channel for this filter
  float* outp = out + (size_t)((n * 32 + b) * 32) * 256;
  const float* b1p = beta1 + (size_t)n * 256 * 1024;
  const float* b2p = beta2 + (size_t)n * 256 * 1024;

  for (int t = 0; t < 256; ++t) {
    // phase a: emit pre-update state, advance cascade
    y_lds[k] = s2;
    float bb1 = b1p[t * 1024 + k];
    float bb2 = b2p[t * 1024 + k];
    float xv = a1nb[cc * 256 + t];
    s2 = bb2 * s2 + (1.0f - bb2) * s1;   // cascade 2 consumes pre-update s1
    s1 = bb1 * s1 + (1.0f - bb1) * xv;
    __syncthreads();

    // phase b: partial dot over this thread's 32 filters
    float p = 0.0f;
#pragma unroll
    for (int i = 0; i < 32; ++i) p += y_lds[q * 32 + i] * wreg[i];
    part[q * 32 + o] = p;
    __syncthreads();

    // phase c: final reduce + activation + store (32 threads)
    if (tid < 32) {
      float z = xz[tid * 257 + t];
#pragma unroll
      for (int qq = 0; qq < 32; ++qq) z += part[qq * 32 + tid];
      outp[tid * 256 + t] = 0.05f + 0.5f * tanhf((z - 0.3f) * 3.0f);
    }
  }
}

// ---------------------------------------------------------------------------
// Launch
// ---------------------------------------------------------------------------
struct KeyPair { uint32_t a, b; };

// jax.random.split(key, 4), PARTITIONABLE (foldlike): key_i = both words of
// threefry2x32(key, (0, i)).
static inline void split4_host(KeyPair key, KeyPair out[4]) {
  for (uint32_t i = 0; i < 4; ++i) {
    uint32_t x0 = 0u, x1 = i;
    tf2x32(key.a, key.b, x0, x1);
    out[i] = {x0, x1};
  }
}

extern "C" void kernel_launch(void* const* d_in, const int* in_sizes, int n_in,
                              void* d_out, int out_size, void* d_ws, size_t ws_size,
                              hipStream_t stream) {
  const float* x   = (const float*)d_in[0];   // (4,32,32,256)
  const float* th1 = (const float*)d_in[1];   // (34,32)
  const float* th2 = (const float*)d_in[2];   // (1058,32)
  const float* Rlf = (const float*)d_in[3];   // (32,32,2)
  const float* Clf = (const float*)d_in[4];   // (32,32,2)
  float* out = (float*)d_out;                 // (4,32,32,256)
  float* ws = (float*)d_ws;

  // workspace layout (floats)
  float* S1   = ws;                  // 4224
  float* den2 = ws + 4224;           // 128
  float* S2   = ws + 4352;           // 135296
  float* a1   = ws + 139648;         // 1048576
  float* be1  = ws + 1188224;        // 1048576
  float* be2  = ws + 2236800;        // 1048576  (total 3285376 floats ~12.6 MB)

  // host-side key chain: key(42) -> k1..k4; split(k2)->R,C,mu,s0; split(k3) same
  KeyPair root{0u, 42u};
  KeyPair kk[4];  split4_host(root, kk);     // kk = {k1, k2, k3, k4}
  KeyPair f1[4];  split4_host(kk[1], f1);    // {kR1, kC1, kmu1, k01}
  KeyPair f2[4];  split4_host(kk[2], f2);    // {kR2, kC2, kmu2, k02}

  w1_kernel<<<dim3(4), dim3(32), 0, stream>>>(th1, S1, kk[0].a, kk[0].b);
  w2a_kernel<<<dim3(4), dim3(256), 0, stream>>>(th2, den2, kk[3].a, kk[3].b);
  w2b_kernel<<<dim3((4 * 1057 * 32 + 255) / 256), dim3(256), 0, stream>>>(
      th2, den2, S2, kk[3].a, kk[3].b);
  p1_kernel<<<dim3(128), dim3(256), 0, stream>>>(x, S1, a1);
  beta_kernel<<<dim3(8192), dim3(256), 0, stream>>>(
      Rlf, Clf, be1, be2,
      f1[0].a, f1[0].b, f1[1].a, f1[1].b, f1[2].a, f1[2].b,
      f2[0].a, f2[0].b, f2[1].a, f2[1].b, f2[2].a, f2[2].b);
  fk_kernel<<<dim3(128), dim3(1024), 0, stream>>>(
      a1, S2, be1, be2, out, f1[3].a, f1[3].b, f2[3].a, f2[3].b);
}

// Round 3
// 239.272 us; speedup vs baseline: 1.5760x; 1.5760x over previous
//
#include <hip/hip_runtime.h>
#include <stdint.h>

// ---------------------------------------------------------------------------
// Problem constants (from reference)
// ---------------------------------------------------------------------------
#define C_RMIN 100000.0f
#define C_RMAX 10000000.0f
#define C_CMIN 1e-07f
#define C_CMAX 1e-04f
#define C_DT   0.1f
#define C_EPS  0.05f
#define C_COUP 0.2f

// ---------------------------------------------------------------------------
// Threefry-2x32 (exact JAX semantics). Host+device.
// ---------------------------------------------------------------------------
__host__ __device__ inline void tf2x32(uint32_t k0, uint32_t k1,
                                       uint32_t& x0, uint32_t& x1) {
  uint32_t ks2 = k0 ^ k1 ^ 0x1BD11BDAu;
  uint32_t a = x0 + k0, b = x1 + k1;
#define TFR(r) a += b; b = (b << (r)) | (b >> (32 - (r))); b ^= a;
  TFR(13) TFR(15) TFR(26) TFR(6)
  a += k1;  b += ks2 + 1u;
  TFR(17) TFR(29) TFR(16) TFR(24)
  a += ks2; b += k0 + 2u;
  TFR(13) TFR(15) TFR(26) TFR(6)
  a += k0;  b += k1 + 3u;
  TFR(17) TFR(29) TFR(16) TFR(24)
  a += k1;  b += ks2 + 4u;
  TFR(13) TFR(15) TFR(26) TFR(6)
  a += ks2; b += k0 + 5u;
#undef TFR
  x0 = a; x1 = b;
}

// jax.random.uniform element e, PARTITIONABLE threefry (jax>=0.5 default):
// one block per element, counter = (0, e), bits = out0 ^ out1.
__device__ inline float unif01(uint32_t k0, uint32_t k1, uint32_t e) {
  uint32_t x0 = 0u, x1 = e;
  tf2x32(k0, k1, x0, x1);
  uint32_t bits = x0 ^ x1;
  return __uint_as_float((bits >> 9) | 0x3F800000u) - 1.0f;
}

__device__ inline float theta_eff(float t) {
  t = fminf(fmaxf(t, -10.0f), 10.0f);
  return (fabsf(t) < 0.01f) ? 0.0f : t;
}

__device__ inline float sigmoidf(float x) { return 1.0f / (1.0f + expf(-x)); }

__device__ inline float noise_mul(float u) { return (u * 2.0f - 1.0f) * C_EPS + 1.0f; }

// ---------------------------------------------------------------------------
// PREP0 (fused): blocks [0,8192) -> beta arrays; [8192,8196) -> S1eff;
//                [8196,8200) -> denom2.
// ---------------------------------------------------------------------------
__global__ __launch_bounds__(256) void prep0_kernel(
    const float* __restrict__ Rlf, const float* __restrict__ Clf,
    const float* __restrict__ theta1, const float* __restrict__ theta2,
    float* __restrict__ beta1, float* __restrict__ beta2,
    float* __restrict__ S1eff, float* __restrict__ denom2,
    uint32_t k1a, uint32_t k1b, uint32_t k4a, uint32_t k4b,
    uint32_t kR1a, uint32_t kR1b, uint32_t kC1a, uint32_t kC1b,
    uint32_t kM1a, uint32_t kM1b,
    uint32_t kR2a, uint32_t kR2b, uint32_t kC2a, uint32_t kC2b,
    uint32_t kM2a, uint32_t kM2b) {
  int bid = blockIdx.x;
  if (bid < 8192) {
    // ---- beta: beta[c][n][t][k], noise e=(t*1024+k)*4+n ----
    int idx = bid * 256 + threadIdx.x;   // 0 .. 2*1048576-1
    int casc = idx >> 20;
    int r = idx & 1048575;
    int n = r >> 18;
    int t = (r >> 10) & 255;
    int k = r & 1023;
    uint32_t e = (uint32_t)((t * 1024 + k) * 4 + n);
    uint32_t ra = casc ? kR2a : kR1a, rb = casc ? kR2b : kR1b;
    uint32_t ca = casc ? kC2a : kC1a, cb = casc ? kC2b : kC1b;
    uint32_t ma = casc ? kM2a : kM1a, mb = casc ? kM2b : kM1b;
    float R_ = Rlf[k * 2 + casc];
    float C_ = Clf[k * 2 + casc];
    float Rt = sigmoidf(R_) * (C_RMAX - C_RMIN) + C_RMIN;
    float Ct = sigmoidf(C_) * (C_CMAX - C_CMIN) + C_CMIN;
    float nR = noise_mul(unif01(ra, rb, e));
    float nC = noise_mul(unif01(ca, cb, e));
    float mu = unif01(ma, mb, e) * C_COUP + 1.0f;
    float rc = mu * (Rt * nR) * (Ct * nC);
    float bt = rc / (rc + C_DT);
    float* outp = casc ? beta2 : beta1;
    outp[(n * 256 + t) * 1024 + k] = bt;
  } else if (bid < 8196) {
    // ---- S1eff[n][m][o], m 0..32 (32=bias). noise e=(n*34+m)*32+o ----
    int n = bid - 8192;
    int o = threadIdx.x;
    if (o < 32) {
      float tn[34];
      float den = 0.0f;
      for (int m = 0; m < 34; ++m) {
        float t = theta_eff(theta1[m * 32 + o]);
        float u = unif01(k1a, k1b, (uint32_t)((n * 34 + m) * 32 + o));
        float v = t * noise_mul(u);
        tn[m] = v;
        den += fabsf(v);
      }
      den += 1e-10f;
      for (int m = 0; m < 33; ++m)
        S1eff[(n * 33 + m) * 32 + o] = tn[m] / den;
    }
  } else {
    // ---- denom2[n][o] = sum_{j<1058} |thn2| + 1e-10. e=(n*1058+j)*32+o ----
    int n = bid - 8196;
    int o = threadIdx.x & 31;
    int jc = threadIdx.x >> 5;          // 0..7
    float part = 0.0f;
    for (int j = jc; j < 1058; j += 8) {
      float t = theta_eff(theta2[j * 32 + o]);
      float u = unif01(k4a, k4b, (uint32_t)((n * 1058 + j) * 32 + o));
      part += fabsf(t * noise_mul(u));
    }
    __shared__ float red[256];
    red[jc * 32 + o] = part;
    __syncthreads();
    if (jc == 0) {
      float s = 0.0f;
      for (int q = 0; q < 8; ++q) s += red[q * 32 + o];
      denom2[n * 32 + o] = s + 1e-10f;
    }
  }
}

// ---------------------------------------------------------------------------
// PREP1 (fused): blocks [0,529) -> S2eff; [529,657) -> a1 (first pmac).
// ---------------------------------------------------------------------------
__global__ __launch_bounds__(256) void prep1_kernel(
    const float* __restrict__ theta2, const float* __restrict__ denom2,
    float* __restrict__ S2eff,
    const float* __restrict__ x, const float* __restrict__ S1eff,
    float* __restrict__ a1, uint32_t k4a, uint32_t k4b) {
  int bid = blockIdx.x;
  __shared__ float xs[32][256];
  if (bid < 529) {
    int idx = bid * 256 + threadIdx.x;
    if (idx >= 4 * 1057 * 32) return;
    int o = idx & 31;
    int r = idx >> 5;
    int j = r % 1057;
    int n = r / 1057;
    float t = theta_eff(theta2[j * 32 + o]);
    float u = unif01(k4a, k4b, (uint32_t)((n * 1058 + j) * 32 + o));
    S2eff[idx] = t * noise_mul(u) / denom2[n * 32 + o];
  } else {
    int blk = bid - 529;
    int n = blk >> 5, b = blk & 31;
    int t = threadIdx.x;
    const float* xp = x + (size_t)((n * 32 + b) * 32) * 256;
    for (int m = 0; m < 32; ++m) xs[m][t] = xp[m * 256 + t];
    __syncthreads();
    const float* S = S1eff + n * 33 * 32;
    float* ap = a1 + (size_t)((n * 32 + b) * 32) * 256;
    for (int o = 0; o < 32; ++o) {
      float z = S[32 * 32 + o];
#pragma unroll
      for (int m = 0; m < 32; ++m) z += xs[m][t] * S[m * 32 + o];
      ap[o * 256 + t] = 0.05f + 0.5f * tanhf((z - 0.3f) * 3.0f);
    }
  }
}

// ---------------------------------------------------------------------------
// FK2: split-K fused filter cascade + partial pmac2 reduction.
// Grid: 256 blocks = (n*32+b)*2 + h; 512 threads; thread owns k = h*512+tid.
// Chunks of Tc=16 timesteps:
//   A: advance recurrence 16 steps, y (pre-update s2) -> ybuf[tc][k_local]
//   B: register-tiled partial dot: thread (kg=tid>>4, o2=tid&15) handles
//      16 k's x 2 o's (o2, o2+16); shfl-reduce 4 kg per wave; -> part LDS
//   C: fold 8 wave-partials -> zpart[(nb,h)][o][t] in ws
// ---------------------------------------------------------------------------
__global__ __launch_bounds__(512) void fk2_kernel(
    const float* __restrict__ a1, const float* __restrict__ S2eff,
    const float* __restrict__ beta1, const float* __restrict__ beta2,
    float* __restrict__ zpart,
    uint32_t k01a, uint32_t k01b, uint32_t k02a, uint32_t k02b) {
  int bid = blockIdx.x;
  int h = bid & 1;
  int nb = bid >> 1;
  int n = nb >> 5;
  int tid = threadIdx.x;

  __shared__ float ybuf[16 * 512];   // [tc][k_local]
  __shared__ float part[8 * 544];    // [wave][o*17 + tc] (pad 17 vs bank conflicts)

  const float* S2n = S2eff + (size_t)n * 1057 * 32;
  int kg = tid >> 4, o2 = tid & 15;

  // weights: 16 k's x 2 o's
  float w_a[16], w_b[16];
#pragma unroll
  for (int i = 0; i < 16; ++i) {
    int k = h * 512 + kg * 16 + i;
    int j = (k >> 5) * 33 + 1 + (k & 31);
    w_a[i] = S2n[j * 32 + o2];
    w_b[i] = S2n[j * 32 + o2 + 16];
  }

  // filter state for k = h*512 + tid
  int k = h * 512 + tid;
  uint32_t e0 = (uint32_t)((k * 4 + n) * 32 + (nb & 31));
  float s1 = unif01(k01a, k01b, e0);
  float s2 = unif01(k02a, k02b, e0);
  int cc = k >> 5;

  const float* a1nb = a1 + (size_t)nb * 32 * 256;            // [c][t]
  const float* b1p = beta1 + (size_t)n * 256 * 1024 + h * 512;
  const float* b2p = beta2 + (size_t)n * 256 * 1024 + h * 512;
  float* zout = zpart + (size_t)bid * 32 * 256;              // [o][t]

  int w = tid >> 6;                 // wave id 0..7
  int lane = tid & 63;

  for (int ch = 0; ch < 16; ++ch) {
    int t0 = ch * 16;
    // ---- phase A: recurrence ----
#pragma unroll
    for (int it = 0; it < 16; ++it) {
      int t = t0 + it;
      ybuf[it * 512 + tid] = s2;
      float bb1 = b1p[t * 1024 + tid];
      float bb2 = b2p[t * 1024 + tid];
      float xv = a1nb[cc * 256 + t];
      s2 = bb2 * s2 + (1.0f - bb2) * s1;   // cascade 2 eats pre-update s1
      s1 = bb1 * s1 + (1.0f - bb1) * xv;
    }
    __syncthreads();

    // ---- phase B: register-tiled partial dot ----
    float acc_a[16], acc_b[16];
#pragma unroll
    for (int tc = 0; tc < 16; ++tc) { acc_a[tc] = 0.0f; acc_b[tc] = 0.0f; }
#pragma unroll
    for (int i = 0; i < 16; i += 4) {
#pragma unroll
      for (int tc = 0; tc < 16; ++tc) {
        const float4 y = *(const float4*)&ybuf[tc * 512 + kg * 16 + i];
        acc_a[tc] += y.x * w_a[i] + y.y * w_a[i + 1] + y.z * w_a[i + 2] + y.w * w_a[i + 3];
        acc_b[tc] += y.x * w_b[i] + y.y * w_b[i + 1] + y.z * w_b[i + 2] + y.w * w_b[i + 3];
      }
    }
    // wave-level reduce over the 4 kg within this wave (lane bits 4,5)
#pragma unroll
    for (int tc = 0; tc < 16; ++tc) {
      acc_a[tc] += __shfl_xor(acc_a[tc], 16, 64);
      acc_a[tc] += __shfl_xor(acc_a[tc], 32, 64);
      acc_b[tc] += __shfl_xor(acc_b[tc], 16, 64);
      acc_b[tc] += __shfl_xor(acc_b[tc], 32, 64);
    }
    if (lane < 16) {   // lane == o2 here
#pragma unroll
      for (int tc = 0; tc < 16; ++tc) {
        part[w * 544 + o2 * 17 + tc] = acc_a[tc];
        part[w * 544 + (o2 + 16) * 17 + tc] = acc_b[tc];
      }
    }
    __syncthreads();

    // ---- phase C: fold wave partials, write zpart ----
    {
      int o = tid >> 4, tc = tid & 15;
      float z = 0.0f;
#pragma unroll
      for (int ww = 0; ww < 8; ++ww) z += part[ww * 544 + o * 17 + tc];
      zout[o * 256 + t0 + tc] = z;
    }
  }
}

// ---------------------------------------------------------------------------
// CB: combine halves + direct-channel term + bias + activation.
// out[n][b][o][t] = act( S2[1056][o] + sum_c a1[c][t]*S2[c*33][o]
//                        + zpart[nb][0][o][t] + zpart[nb][1][o][t] )
// ---------------------------------------------------------------------------
__global__ __launch_bounds__(256) void cb_kernel(
    const float* __restrict__ a1, const float* __restrict__ S2eff,
    const float* __restrict__ zpart, float* __restrict__ out) {
  int nb = blockIdx.x;
  int n = nb >> 5;
  int t = threadIdx.x;
  __shared__ float xs[32][256];
  const float* a1nb = a1 + (size_t)nb * 32 * 256;
  for (int c = 0; c < 32; ++c) xs[c][t] = a1nb[c * 256 + t];
  __syncthreads();
  const float* S2n = S2eff + (size_t)n * 1057 * 32;
  const float* zp0 = zpart + (size_t)(nb * 2 + 0) * 8192;
  const float* zp1 = zpart + (size_t)(nb * 2 + 1) * 8192;
  float* op = out + (size_t)nb * 8192;
  for (int o = 0; o < 32; ++o) {
    float z = S2n[1056 * 32 + o];
#pragma unroll
    for (int c = 0; c < 32; ++c) z += xs[c][t] * S2n[(c * 33) * 32 + o];
    z += zp0[o * 256 + t] + zp1[o * 256 + t];
    op[o * 256 + t] = 0.05f + 0.5f * tanhf((z - 0.3f) * 3.0f);
  }
}

// ---------------------------------------------------------------------------
// Launch
// ---------------------------------------------------------------------------
struct KeyPair { uint32_t a, b; };

// jax.random.split(key, 4), PARTITIONABLE (foldlike): key_i = threefry(key,(0,i))
static inline void split4_host(KeyPair key, KeyPair out[4]) {
  for (uint32_t i = 0; i < 4; ++i) {
    uint32_t x0 = 0u, x1 = i;
    tf2x32(key.a, key.b, x0, x1);
    out[i] = {x0, x1};
  }
}

extern "C" void kernel_launch(void* const* d_in, const int* in_sizes, int n_in,
                              void* d_out, int out_size, void* d_ws, size_t ws_size,
                              hipStream_t stream) {
  const float* x   = (const float*)d_in[0];   // (4,32,32,256)
  const float* th1 = (const float*)d_in[1];   // (34,32)
  const float* th2 = (const float*)d_in[2];   // (1058,32)
  const float* Rlf = (const float*)d_in[3];   // (32,32,2)
  const float* Clf = (const float*)d_in[4];   // (32,32,2)
  float* out = (float*)d_out;                 // (4,32,32,256)
  float* ws = (float*)d_ws;

  // workspace layout (floats)
  float* S1    = ws;                  // 4224
  float* den2  = ws + 4224;           // 128
  float* S2    = ws + 4352;           // 135296
  float* a1    = ws + 139648;         // 1048576
  float* be1   = ws + 1188224;        // 1048576
  float* be2   = ws + 2236800;        // 1048576
  float* zpart = ws + 3285376;        // 2097152  (total 5382528 floats ~21.5 MB)

  // host-side key chain: key(42) -> k1..k4; split(k2)->{R,C,mu,s0}_1; split(k3) same
  KeyPair root{0u, 42u};
  KeyPair kk[4];  split4_host(root, kk);     // {k1, k2, k3, k4}
  KeyPair f1[4];  split4_host(kk[1], f1);    // {kR1, kC1, kmu1, k01}
  KeyPair f2[4];  split4_host(kk[2], f2);    // {kR2, kC2, kmu2, k02}

  prep0_kernel<<<dim3(8200), dim3(256), 0, stream>>>(
      Rlf, Clf, th1, th2, be1, be2, S1, den2,
      kk[0].a, kk[0].b, kk[3].a, kk[3].b,
      f1[0].a, f1[0].b, f1[1].a, f1[1].b, f1[2].a, f1[2].b,
      f2[0].a, f2[0].b, f2[1].a, f2[1].b, f2[2].a, f2[2].b);
  prep1_kernel<<<dim3(657), dim3(256), 0, stream>>>(
      th2, den2, S2, x, S1, a1, kk[3].a, kk[3].b);
  fk2_kernel<<<dim3(256), dim3(512), 0, stream>>>(
      a1, S2, be1, be2, zpart, f1[3].a, f1[3].b, f2[3].a, f2[3].b);
  cb_kernel<<<dim3(128), dim3(256), 0, stream>>>(a1, S2, zpart, out);
}

// Round 4
// 196.271 us; speedup vs baseline: 1.9213x; 1.2191x over previous
//
#include <hip/hip_runtime.h>
#include <stdint.h>

// ---------------------------------------------------------------------------
// Problem constants (from reference)
// ---------------------------------------------------------------------------
#define C_RMIN 100000.0f
#define C_RMAX 10000000.0f
#define C_CMIN 1e-07f
#define C_CMAX 1e-04f
#define C_DT   0.1f
#define C_EPS  0.05f
#define C_COUP 0.2f

typedef __attribute__((ext_vector_type(8))) short bf16x8;
typedef __attribute__((ext_vector_type(4))) float floatx4;
union FragU { uint32_t u[4]; bf16x8 s; };

// ---------------------------------------------------------------------------
// Threefry-2x32 (exact JAX semantics). Host+device.
// ---------------------------------------------------------------------------
__host__ __device__ inline void tf2x32(uint32_t k0, uint32_t k1,
                                       uint32_t& x0, uint32_t& x1) {
  uint32_t ks2 = k0 ^ k1 ^ 0x1BD11BDAu;
  uint32_t a = x0 + k0, b = x1 + k1;
#define TFR(r) a += b; b = (b << (r)) | (b >> (32 - (r))); b ^= a;
  TFR(13) TFR(15) TFR(26) TFR(6)
  a += k1;  b += ks2 + 1u;
  TFR(17) TFR(29) TFR(16) TFR(24)
  a += ks2; b += k0 + 2u;
  TFR(13) TFR(15) TFR(26) TFR(6)
  a += k0;  b += k1 + 3u;
  TFR(17) TFR(29) TFR(16) TFR(24)
  a += k1;  b += ks2 + 4u;
  TFR(13) TFR(15) TFR(26) TFR(6)
  a += ks2; b += k0 + 5u;
#undef TFR
  x0 = a; x1 = b;
}

// jax.random.uniform element e, PARTITIONABLE threefry (jax>=0.5 default):
// one block per element, counter = (0, e), bits = out0 ^ out1.
__device__ inline float unif01(uint32_t k0, uint32_t k1, uint32_t e) {
  uint32_t x0 = 0u, x1 = e;
  tf2x32(k0, k1, x0, x1);
  uint32_t bits = x0 ^ x1;
  return __uint_as_float((bits >> 9) | 0x3F800000u) - 1.0f;
}

__device__ inline float theta_eff(float t) {
  t = fminf(fmaxf(t, -10.0f), 10.0f);
  return (fabsf(t) < 0.01f) ? 0.0f : t;
}

__device__ inline float sigmoidf(float x) { return 1.0f / (1.0f + expf(-x)); }

__device__ inline float noise_mul(float u) { return (u * 2.0f - 1.0f) * C_EPS + 1.0f; }

// ---------------------------------------------------------------------------
// PREP0 (fused): blocks [0,8192) -> beta arrays; [8192,8196) -> S1eff;
//                [8196,8200) -> denom2.
// ---------------------------------------------------------------------------
__global__ __launch_bounds__(256) void prep0_kernel(
    const float* __restrict__ Rlf, const float* __restrict__ Clf,
    const float* __restrict__ theta1, const float* __restrict__ theta2,
    float* __restrict__ beta1, float* __restrict__ beta2,
    float* __restrict__ S1eff, float* __restrict__ denom2,
    uint32_t k1a, uint32_t k1b, uint32_t k4a, uint32_t k4b,
    uint32_t kR1a, uint32_t kR1b, uint32_t kC1a, uint32_t kC1b,
    uint32_t kM1a, uint32_t kM1b,
    uint32_t kR2a, uint32_t kR2b, uint32_t kC2a, uint32_t kC2b,
    uint32_t kM2a, uint32_t kM2b) {
  int bid = blockIdx.x;
  if (bid < 8192) {
    int idx = bid * 256 + threadIdx.x;   // 0 .. 2*1048576-1
    int casc = idx >> 20;
    int r = idx & 1048575;
    int n = r >> 18;
    int t = (r >> 10) & 255;
    int k = r & 1023;
    uint32_t e = (uint32_t)((t * 1024 + k) * 4 + n);
    uint32_t ra = casc ? kR2a : kR1a, rb = casc ? kR2b : kR1b;
    uint32_t ca = casc ? kC2a : kC1a, cb = casc ? kC2b : kC1b;
    uint32_t ma = casc ? kM2a : kM1a, mb = casc ? kM2b : kM1b;
    float R_ = Rlf[k * 2 + casc];
    float C_ = Clf[k * 2 + casc];
    float Rt = sigmoidf(R_) * (C_RMAX - C_RMIN) + C_RMIN;
    float Ct = sigmoidf(C_) * (C_CMAX - C_CMIN) + C_CMIN;
    float nR = noise_mul(unif01(ra, rb, e));
    float nC = noise_mul(unif01(ca, cb, e));
    float mu = unif01(ma, mb, e) * C_COUP + 1.0f;
    float rc = mu * (Rt * nR) * (Ct * nC);
    float bt = rc / (rc + C_DT);
    float* outp = casc ? beta2 : beta1;
    outp[(n * 256 + t) * 1024 + k] = bt;
  } else if (bid < 8196) {
    int n = bid - 8192;
    int o = threadIdx.x;
    if (o < 32) {
      float tn[34];
      float den = 0.0f;
      for (int m = 0; m < 34; ++m) {
        float t = theta_eff(theta1[m * 32 + o]);
        float u = unif01(k1a, k1b, (uint32_t)((n * 34 + m) * 32 + o));
        float v = t * noise_mul(u);
        tn[m] = v;
        den += fabsf(v);
      }
      den += 1e-10f;
      for (int m = 0; m < 33; ++m)
        S1eff[(n * 33 + m) * 32 + o] = tn[m] / den;
    }
  } else {
    int n = bid - 8196;
    int o = threadIdx.x & 31;
    int jc = threadIdx.x >> 5;          // 0..7
    float part = 0.0f;
    for (int j = jc; j < 1058; j += 8) {
      float t = theta_eff(theta2[j * 32 + o]);
      float u = unif01(k4a, k4b, (uint32_t)((n * 1058 + j) * 32 + o));
      part += fabsf(t * noise_mul(u));
    }
    __shared__ float red[256];
    red[jc * 32 + o] = part;
    __syncthreads();
    if (jc == 0) {
      float s = 0.0f;
      for (int q = 0; q < 8; ++q) s += red[q * 32 + o];
      denom2[n * 32 + o] = s + 1e-10f;
    }
  }
}

// ---------------------------------------------------------------------------
// PREP1 (fused): blocks [0,529) -> S2eff; [529,657) -> a1 (first pmac).
// ---------------------------------------------------------------------------
__global__ __launch_bounds__(256) void prep1_kernel(
    const float* __restrict__ theta2, const float* __restrict__ denom2,
    float* __restrict__ S2eff,
    const float* __restrict__ x, const float* __restrict__ S1eff,
    float* __restrict__ a1, uint32_t k4a, uint32_t k4b) {
  int bid = blockIdx.x;
  __shared__ float xs[32][256];
  if (bid < 529) {
    int idx = bid * 256 + threadIdx.x;
    if (idx >= 4 * 1057 * 32) return;
    int o = idx & 31;
    int r = idx >> 5;
    int j = r % 1057;
    int n = r / 1057;
    float t = theta_eff(theta2[j * 32 + o]);
    float u = unif01(k4a, k4b, (uint32_t)((n * 1058 + j) * 32 + o));
    S2eff[idx] = t * noise_mul(u) / denom2[n * 32 + o];
  } else {
    int blk = bid - 529;
    int n = blk >> 5, b = blk & 31;
    int t = threadIdx.x;
    const float* xp = x + (size_t)((n * 32 + b) * 32) * 256;
    for (int m = 0; m < 32; ++m) xs[m][t] = xp[m * 256 + t];
    __syncthreads();
    const float* S = S1eff + n * 33 * 32;
    float* ap = a1 + (size_t)((n * 32 + b) * 32) * 256;
    for (int o = 0; o < 32; ++o) {
      float z = S[32 * 32 + o];
#pragma unroll
      for (int m = 0; m < 32; ++m) z += xs[m][t] * S[m * 32 + o];
      ap[o * 256 + t] = 0.05f + 0.5f * tanhf((z - 0.3f) * 3.0f);
    }
  }
}

// ---------------------------------------------------------------------------
// FK3: producer/consumer MFMA fused filter cascade + partial pmac2.
// Grid: 512 blocks = (nb = n*32+b)*4 + qr; 320 threads.
//   tid 0..255  : producers, filter k = qr*256 + tid (recurrence)
//   tid 256..319: consumer wave, MFMA Z[16t][32o] += Y[16t][256k]*W[256k][32o]
// Double-buffered packed-bf16 y tile; 1 barrier per 16-step chunk.
// zpart[bid][o][t] partials combined by cb_kernel.
// ---------------------------------------------------------------------------
#define YPAD 260
#define YBUF (16 * YPAD)

__global__ __launch_bounds__(320) void fk3_kernel(
    const float* __restrict__ a1, const float* __restrict__ S2eff,
    const float* __restrict__ beta1, const float* __restrict__ beta2,
    float* __restrict__ zpart,
    uint32_t k01a, uint32_t k01b, uint32_t k02a, uint32_t k02b) {
  int bid = blockIdx.x;
  int qr = bid & 3;
  int nb = bid >> 2;
  int n = nb >> 5, b = nb & 31;
  int tid = threadIdx.x;

  __shared__ __align__(16) uint32_t yb[2 * YBUF];   // packed (lo16<<16)|hi16
  __shared__ __align__(16) short wf[16 * 512];      // [ks*2+ot][lane][8] bf16 B-frags

  const float* S2n = S2eff + (size_t)n * 1057 * 32;
  const float* a1nb = a1 + (size_t)nb * 8192;
  const float* b1p = beta1 + (size_t)n * 262144 + qr * 256;
  const float* b2p = beta2 + (size_t)n * 262144 + qr * 256;
  float* zout = zpart + (size_t)bid * 8192;

  float s1 = 0.0f, s2 = 0.0f;
  int cc = 0;

  if (tid < 256) {
    // producer init: s0 states + build W bf16 B-fragments in LDS
    int k = qr * 256 + tid;
    uint32_t e0 = (uint32_t)((k * 4 + n) * 32 + b);
    s1 = unif01(k01a, k01b, e0);
    s2 = unif01(k02a, k02b, e0);
    cc = k >> 5;
    for (int it = 0; it < 32; ++it) {
      int widx = it * 256 + tid;            // [0, 8192)
      int j = widx & 7;
      int lane_ = (widx >> 3) & 63;
      int ot = (widx >> 9) & 1;
      int ks = widx >> 10;                  // 0..7
      int sub = ((lane_ >> 4) << 3) + j;    // k within 32-chunk
      int jrow = (qr * 8 + ks) * 33 + 1 + sub;
      float w = S2n[jrow * 32 + ot * 16 + (lane_ & 15)];
      uint32_t wb = __float_as_uint(w);
      uint32_t hi = (wb + 0x7FFFu + ((wb >> 16) & 1u)) >> 16;   // RNE bf16
      wf[(ks * 2 + ot) * 512 + lane_ * 8 + j] = (short)(uint16_t)hi;
    }
  }
  __syncthreads();

  for (int c = 0; c <= 16; ++c) {
    if (tid < 256) {
      if (c < 16) {
        // ---- produce chunk c: 16 recurrence steps into yb[c&1] ----
        uint32_t* ybw = yb + (c & 1) * YBUF;
        int t0 = c * 16;
#pragma unroll
        for (int it = 0; it < 16; ++it) {
          int t = t0 + it;
          uint32_t sb = __float_as_uint(s2);
          uint32_t hi = sb >> 16;
          float fhi = __uint_as_float(sb & 0xFFFF0000u);
          uint32_t lo = __float_as_uint(s2 - fhi) >> 16;   // exact split
          ybw[it * YPAD + tid] = (lo << 16) | hi;
          float bb1 = b1p[t * 1024 + tid];
          float bb2 = b2p[t * 1024 + tid];
          float xv = a1nb[cc * 256 + t];
          s2 = bb2 * s2 + (1.0f - bb2) * s1;   // cascade 2 eats pre-update s1
          s1 = bb1 * s1 + (1.0f - bb1) * xv;
        }
      }
    } else if (c >= 1) {
      // ---- consume chunk c-1 from yb[(c-1)&1] ----
      const uint32_t* ybr = yb + ((c - 1) & 1) * YBUF;
      int lane = tid - 256;
      int tc = lane & 15, q = lane >> 4;
      const uint32_t* yrow = ybr + tc * YPAD + q * 8;
      floatx4 acc0a = {0,0,0,0}, acc0b = {0,0,0,0};
      floatx4 acc1a = {0,0,0,0}, acc1b = {0,0,0,0};
#pragma unroll
      for (int ks = 0; ks < 8; ++ks) {
        uint4 p0 = *(const uint4*)(yrow + ks * 32);
        uint4 p1 = *(const uint4*)(yrow + ks * 32 + 4);
        FragU ah, al;
        ah.u[0] = (p0.x & 0xFFFFu) | (p0.y << 16);
        ah.u[1] = (p0.z & 0xFFFFu) | (p0.w << 16);
        ah.u[2] = (p1.x & 0xFFFFu) | (p1.y << 16);
        ah.u[3] = (p1.z & 0xFFFFu) | (p1.w << 16);
        al.u[0] = (p0.x >> 16) | (p0.y & 0xFFFF0000u);
        al.u[1] = (p0.z >> 16) | (p0.w & 0xFFFF0000u);
        al.u[2] = (p1.x >> 16) | (p1.w & 0u) | (p1.y & 0xFFFF0000u);
        al.u[3] = (p1.z >> 16) | (p1.w & 0xFFFF0000u);
        bf16x8 bh0 = *(const bf16x8*)&wf[(ks * 2 + 0) * 512 + lane * 8];
        bf16x8 bh1 = *(const bf16x8*)&wf[(ks * 2 + 1) * 512 + lane * 8];
        if (ks & 1) {
          acc0b = __builtin_amdgcn_mfma_f32_16x16x32_bf16(ah.s, bh0, acc0b, 0, 0, 0);
          acc0b = __builtin_amdgcn_mfma_f32_16x16x32_bf16(al.s, bh0, acc0b, 0, 0, 0);
          acc1b = __builtin_amdgcn_mfma_f32_16x16x32_bf16(ah.s, bh1, acc1b, 0, 0, 0);
          acc1b = __builtin_amdgcn_mfma_f32_16x16x32_bf16(al.s, bh1, acc1b, 0, 0, 0);
        } else {
          acc0a = __builtin_amdgcn_mfma_f32_16x16x32_bf16(ah.s, bh0, acc0a, 0, 0, 0);
          acc0a = __builtin_amdgcn_mfma_f32_16x16x32_bf16(al.s, bh0, acc0a, 0, 0, 0);
          acc1a = __builtin_amdgcn_mfma_f32_16x16x32_bf16(ah.s, bh1, acc1a, 0, 0, 0);
          acc1a = __builtin_amdgcn_mfma_f32_16x16x32_bf16(al.s, bh1, acc1a, 0, 0, 0);
        }
      }
      int t0 = (c - 1) * 16;
      floatx4 r0 = acc0a + acc0b;
      floatx4 r1 = acc1a + acc1b;
      // D layout: col = lane&15 (=o within tile), row = q*4 + reg (=t_local)
      *(floatx4*)&zout[tc * 256 + t0 + q * 4] = r0;
      *(floatx4*)&zout[(16 + tc) * 256 + t0 + q * 4] = r1;
    }
    __syncthreads();
  }
}

// ---------------------------------------------------------------------------
// CB: combine 4 K-quarters + direct-channel term + bias + activation.
// ---------------------------------------------------------------------------
__global__ __launch_bounds__(256) void cb_kernel(
    const float* __restrict__ a1, const float* __restrict__ S2eff,
    const float* __restrict__ zpart, float* __restrict__ out) {
  int nb = blockIdx.x;
  int n = nb >> 5;
  int t = threadIdx.x;
  __shared__ float xs[32][256];
  const float* a1nb = a1 + (size_t)nb * 8192;
  for (int c = 0; c < 32; ++c) xs[c][t] = a1nb[c * 256 + t];
  __syncthreads();
  const float* S2n = S2eff + (size_t)n * 1057 * 32;
  const float* zp = zpart + (size_t)nb * 4 * 8192;
  float* op = out + (size_t)nb * 8192;
  for (int o = 0; o < 32; ++o) {
    float z = S2n[1056 * 32 + o];
#pragma unroll
    for (int c = 0; c < 32; ++c) z += xs[c][t] * S2n[(c * 33) * 32 + o];
    z += zp[o * 256 + t] + zp[8192 + o * 256 + t] +
         zp[16384 + o * 256 + t] + zp[24576 + o * 256 + t];
    op[o * 256 + t] = 0.05f + 0.5f * tanhf((z - 0.3f) * 3.0f);
  }
}

// ---------------------------------------------------------------------------
// Launch
// ---------------------------------------------------------------------------
struct KeyPair { uint32_t a, b; };

// jax.random.split(key, 4), PARTITIONABLE (foldlike): key_i = threefry(key,(0,i))
static inline void split4_host(KeyPair key, KeyPair out[4]) {
  for (uint32_t i = 0; i < 4; ++i) {
    uint32_t x0 = 0u, x1 = i;
    tf2x32(key.a, key.b, x0, x1);
    out[i] = {x0, x1};
  }
}

extern "C" void kernel_launch(void* const* d_in, const int* in_sizes, int n_in,
                              void* d_out, int out_size, void* d_ws, size_t ws_size,
                              hipStream_t stream) {
  const float* x   = (const float*)d_in[0];   // (4,32,32,256)
  const float* th1 = (const float*)d_in[1];   // (34,32)
  const float* th2 = (const float*)d_in[2];   // (1058,32)
  const float* Rlf = (const float*)d_in[3];   // (32,32,2)
  const float* Clf = (const float*)d_in[4];   // (32,32,2)
  float* out = (float*)d_out;                 // (4,32,32,256)
  float* ws = (float*)d_ws;

  // workspace layout (floats)
  float* S1    = ws;                  // 4224
  float* den2  = ws + 4224;           // 128
  float* S2    = ws + 4352;           // 135296
  float* a1    = ws + 139648;         // 1048576
  float* be1   = ws + 1188224;        // 1048576
  float* be2   = ws + 2236800;        // 1048576
  float* zpart = ws + 3285376;        // 4194304 (512 blocks x 8192) ~29.9 MB total

  KeyPair root{0u, 42u};
  KeyPair kk[4];  split4_host(root, kk);     // {k1, k2, k3, k4}
  KeyPair f1[4];  split4_host(kk[1], f1);    // {kR1, kC1, kmu1, k01}
  KeyPair f2[4];  split4_host(kk[2], f2);    // {kR2, kC2, kmu2, k02}

  prep0_kernel<<<dim3(8200), dim3(256), 0, stream>>>(
      Rlf, Clf, th1, th2, be1, be2, S1, den2,
      kk[0].a, kk[0].b, kk[3].a, kk[3].b,
      f1[0].a, f1[0].b, f1[1].a, f1[1].b, f1[2].a, f1[2].b,
      f2[0].a, f2[0].b, f2[1].a, f2[1].b, f2[2].a, f2[2].b);
  prep1_kernel<<<dim3(657), dim3(256), 0, stream>>>(
      th2, den2, S2, x, S1, a1, kk[3].a, kk[3].b);
  fk3_kernel<<<dim3(512), dim3(320), 0, stream>>>(
      a1, S2, be1, be2, zpart, f1[3].a, f1[3].b, f2[3].a, f2[3].b);
  cb_kernel<<<dim3(128), dim3(256), 0, stream>>>(a1, S2, zpart, out);
}

// Round 5
// 161.294 us; speedup vs baseline: 2.3379x; 1.2169x over previous
//
#include <hip/hip_runtime.h>
#include <stdint.h>

// ---------------------------------------------------------------------------
// Problem constants (from reference)
// ---------------------------------------------------------------------------
#define C_RMIN 100000.0f
#define C_RMAX 10000000.0f
#define C_CMIN 1e-07f
#define C_CMAX 1e-04f
#define C_DT   0.1f
#define C_EPS  0.05f
#define C_COUP 0.2f

typedef __attribute__((ext_vector_type(8))) short bf16x8;
typedef __attribute__((ext_vector_type(4))) float floatx4;
union FragU { uint32_t u[4]; bf16x8 s; };

// ---------------------------------------------------------------------------
// Threefry-2x32 (exact JAX semantics). Host+device.
// ---------------------------------------------------------------------------
__host__ __device__ inline void tf2x32(uint32_t k0, uint32_t k1,
                                       uint32_t& x0, uint32_t& x1) {
  uint32_t ks2 = k0 ^ k1 ^ 0x1BD11BDAu;
  uint32_t a = x0 + k0, b = x1 + k1;
#define TFR(r) a += b; b = (b << (r)) | (b >> (32 - (r))); b ^= a;
  TFR(13) TFR(15) TFR(26) TFR(6)
  a += k1;  b += ks2 + 1u;
  TFR(17) TFR(29) TFR(16) TFR(24)
  a += ks2; b += k0 + 2u;
  TFR(13) TFR(15) TFR(26) TFR(6)
  a += k0;  b += k1 + 3u;
  TFR(17) TFR(29) TFR(16) TFR(24)
  a += k1;  b += ks2 + 4u;
  TFR(13) TFR(15) TFR(26) TFR(6)
  a += ks2; b += k0 + 5u;
#undef TFR
  x0 = a; x1 = b;
}

// jax.random.uniform element e, PARTITIONABLE threefry (jax>=0.5 default):
// one block per element, counter = (0, e), bits = out0 ^ out1.
__device__ inline float unif01(uint32_t k0, uint32_t k1, uint32_t e) {
  uint32_t x0 = 0u, x1 = e;
  tf2x32(k0, k1, x0, x1);
  uint32_t bits = x0 ^ x1;
  return __uint_as_float((bits >> 9) | 0x3F800000u) - 1.0f;
}

__device__ inline float theta_eff(float t) {
  t = fminf(fmaxf(t, -10.0f), 10.0f);
  return (fabsf(t) < 0.01f) ? 0.0f : t;
}

__device__ inline float sigmoidf(float x) { return 1.0f / (1.0f + expf(-x)); }

__device__ inline float noise_mul(float u) { return (u * 2.0f - 1.0f) * C_EPS + 1.0f; }

// ---------------------------------------------------------------------------
// PREP0 (fused, heavy-work-first dispatch order):
//   bids [0,32)    -> denom2 partials (n = bid>>3, p = bid&7), 64-way j split
//   bids [32,36)   -> S1eff (n = bid-32)
//   bids [36,1060) -> beta arrays, one thread = 8 timesteps of one (casc,n,k)
// ---------------------------------------------------------------------------
__global__ __launch_bounds__(256) void prep0_kernel(
    const float* __restrict__ Rlf, const float* __restrict__ Clf,
    const float* __restrict__ theta1, const float* __restrict__ theta2,
    float* __restrict__ beta1, float* __restrict__ beta2,
    float* __restrict__ S1eff, float* __restrict__ denom2p,
    uint32_t k1a, uint32_t k1b, uint32_t k4a, uint32_t k4b,
    uint32_t kR1a, uint32_t kR1b, uint32_t kC1a, uint32_t kC1b,
    uint32_t kM1a, uint32_t kM1b,
    uint32_t kR2a, uint32_t kR2b, uint32_t kC2a, uint32_t kC2b,
    uint32_t kM2a, uint32_t kM2b) {
  int bid = blockIdx.x;
  if (bid < 32) {
    // ---- denom2 partials: denom2p[(n*8+p)*32+o] = sum over j in lane-set ----
    int n = bid >> 3, p = bid & 7;
    int o = threadIdx.x & 31;
    int jc = threadIdx.x >> 5;          // 0..7
    int j0 = p * 8 + jc;                // 0..63
    float part = 0.0f;
    for (int j = j0; j < 1058; j += 64) {
      float t = theta_eff(theta2[j * 32 + o]);
      float u = unif01(k4a, k4b, (uint32_t)((n * 1058 + j) * 32 + o));
      part += fabsf(t * noise_mul(u));
    }
    __shared__ float red[256];
    red[jc * 32 + o] = part;
    __syncthreads();
    if (jc == 0) {
      float s = 0.0f;
      for (int q = 0; q < 8; ++q) s += red[q * 32 + o];
      denom2p[(n * 8 + p) * 32 + o] = s;
    }
  } else if (bid < 36) {
    // ---- S1eff[n][m][o], m 0..32 (32=bias). noise e=(n*34+m)*32+o ----
    int n = bid - 32;
    int o = threadIdx.x;
    if (o < 32) {
      float tn[34];
      float den = 0.0f;
      for (int m = 0; m < 34; ++m) {
        float t = theta_eff(theta1[m * 32 + o]);
        float u = unif01(k1a, k1b, (uint32_t)((n * 34 + m) * 32 + o));
        float v = t * noise_mul(u);
        tn[m] = v;
        den += fabsf(v);
      }
      den += 1e-10f;
      for (int m = 0; m < 33; ++m)
        S1eff[(n * 33 + m) * 32 + o] = tn[m] / den;
    }
  } else {
    // ---- beta: thread handles 8 t's for fixed (casc,n,k) ----
    int u = (bid - 36) * 256 + threadIdx.x;   // [0, 262144)
    int k = u & 1023;
    int tc = (u >> 10) & 31;
    int n = (u >> 15) & 3;
    int casc = u >> 17;
    uint32_t ra = casc ? kR2a : kR1a, rb = casc ? kR2b : kR1b;
    uint32_t ca = casc ? kC2a : kC1a, cb = casc ? kC2b : kC1b;
    uint32_t ma = casc ? kM2a : kM1a, mb = casc ? kM2b : kM1b;
    float R_ = Rlf[k * 2 + casc];
    float C_ = Clf[k * 2 + casc];
    float Rt = sigmoidf(R_) * (C_RMAX - C_RMIN) + C_RMIN;
    float Ct = sigmoidf(C_) * (C_CMAX - C_CMIN) + C_CMIN;
    float* outp = casc ? beta2 : beta1;
#pragma unroll
    for (int it = 0; it < 8; ++it) {
      int t = tc * 8 + it;
      uint32_t e = (uint32_t)((t * 1024 + k) * 4 + n);
      float nR = noise_mul(unif01(ra, rb, e));
      float nC = noise_mul(unif01(ca, cb, e));
      float mu = unif01(ma, mb, e) * C_COUP + 1.0f;
      float rc = mu * (Rt * nR) * (Ct * nC);
      outp[(n * 256 + t) * 1024 + k] = rc / (rc + C_DT);
    }
  }
}

// ---------------------------------------------------------------------------
// PREP1 (fused, heavy-first): bids [0,128) -> a1 (first pmac);
//                             bids [128,657) -> S2eff (sums denom partials).
// ---------------------------------------------------------------------------
__global__ __launch_bounds__(256) void prep1_kernel(
    const float* __restrict__ theta2, const float* __restrict__ denom2p,
    float* __restrict__ S2eff,
    const float* __restrict__ x, const float* __restrict__ S1eff,
    float* __restrict__ a1, uint32_t k4a, uint32_t k4b) {
  int bid = blockIdx.x;
  __shared__ float xs[32][256];
  if (bid < 128) {
    int n = bid >> 5, b = bid & 31;
    int t = threadIdx.x;
    const float* xp = x + (size_t)((n * 32 + b) * 32) * 256;
    for (int m = 0; m < 32; ++m) xs[m][t] = xp[m * 256 + t];
    __syncthreads();
    const float* S = S1eff + n * 33 * 32;
    float* ap = a1 + (size_t)((n * 32 + b) * 32) * 256;
    for (int o = 0; o < 32; ++o) {
      float z = S[32 * 32 + o];
#pragma unroll
      for (int m = 0; m < 32; ++m) z += xs[m][t] * S[m * 32 + o];
      ap[o * 256 + t] = 0.05f + 0.5f * tanhf((z - 0.3f) * 3.0f);
    }
  } else {
    int idx = (bid - 128) * 256 + threadIdx.x;
    if (idx >= 4 * 1057 * 32) return;
    int o = idx & 31;
    int r = idx >> 5;
    int j = r % 1057;
    int n = r / 1057;
    float den = 1e-10f;
#pragma unroll
    for (int p = 0; p < 8; ++p) den += denom2p[(n * 8 + p) * 32 + o];
    float t = theta_eff(theta2[j * 32 + o]);
    float u = unif01(k4a, k4b, (uint32_t)((n * 1058 + j) * 32 + o));
    S2eff[idx] = t * noise_mul(u) / den;
  }
}

// ---------------------------------------------------------------------------
// FK3: producer/consumer MFMA fused filter cascade + partial pmac2.
// Grid: 512 blocks = (nb = n*32+b)*4 + qr; 320 threads.
//   tid 0..255  : producers, filter k = qr*256 + tid (recurrence)
//   tid 256..319: consumer wave, MFMA Z[16t][32o] += Y[16t][256k]*W[256k][32o]
// Double-buffered packed-bf16 y tile; 1 barrier per 16-step chunk.
// ---------------------------------------------------------------------------
#define YPAD 260
#define YBUF (16 * YPAD)

__global__ __launch_bounds__(320) void fk3_kernel(
    const float* __restrict__ a1, const float* __restrict__ S2eff,
    const float* __restrict__ beta1, const float* __restrict__ beta2,
    float* __restrict__ zpart,
    uint32_t k01a, uint32_t k01b, uint32_t k02a, uint32_t k02b) {
  int bid = blockIdx.x;
  int qr = bid & 3;
  int nb = bid >> 2;
  int n = nb >> 5, b = nb & 31;
  int tid = threadIdx.x;

  __shared__ __align__(16) uint32_t yb[2 * YBUF];   // packed (lo16<<16)|hi16
  __shared__ __align__(16) short wf[16 * 512];      // [ks*2+ot][lane][8] bf16 B-frags

  const float* S2n = S2eff + (size_t)n * 1057 * 32;
  const float* a1nb = a1 + (size_t)nb * 8192;
  const float* b1p = beta1 + (size_t)n * 262144 + qr * 256;
  const float* b2p = beta2 + (size_t)n * 262144 + qr * 256;
  float* zout = zpart + (size_t)bid * 8192;

  float s1 = 0.0f, s2 = 0.0f;
  int cc = 0;

  if (tid < 256) {
    int k = qr * 256 + tid;
    uint32_t e0 = (uint32_t)((k * 4 + n) * 32 + b);
    s1 = unif01(k01a, k01b, e0);
    s2 = unif01(k02a, k02b, e0);
    cc = k >> 5;
    for (int it = 0; it < 32; ++it) {
      int widx = it * 256 + tid;            // [0, 8192)
      int j = widx & 7;
      int lane_ = (widx >> 3) & 63;
      int ot = (widx >> 9) & 1;
      int ks = widx >> 10;                  // 0..7
      int sub = ((lane_ >> 4) << 3) + j;    // k within 32-chunk
      int jrow = (qr * 8 + ks) * 33 + 1 + sub;
      float w = S2n[jrow * 32 + ot * 16 + (lane_ & 15)];
      uint32_t wb = __float_as_uint(w);
      uint32_t hi = (wb + 0x7FFFu + ((wb >> 16) & 1u)) >> 16;   // RNE bf16
      wf[(ks * 2 + ot) * 512 + lane_ * 8 + j] = (short)(uint16_t)hi;
    }
  }
  __syncthreads();

  for (int c = 0; c <= 16; ++c) {
    if (tid < 256) {
      if (c < 16) {
        uint32_t* ybw = yb + (c & 1) * YBUF;
        int t0 = c * 16;
#pragma unroll
        for (int it = 0; it < 16; ++it) {
          int t = t0 + it;
          uint32_t sb = __float_as_uint(s2);
          uint32_t hi = sb >> 16;
          float fhi = __uint_as_float(sb & 0xFFFF0000u);
          uint32_t lo = __float_as_uint(s2 - fhi) >> 16;   // exact split
          ybw[it * YPAD + tid] = (lo << 16) | hi;
          float bb1 = b1p[t * 1024 + tid];
          float bb2 = b2p[t * 1024 + tid];
          float xv = a1nb[cc * 256 + t];
          s2 = bb2 * s2 + (1.0f - bb2) * s1;   // cascade 2 eats pre-update s1
          s1 = bb1 * s1 + (1.0f - bb1) * xv;
        }
      }
    } else if (c >= 1) {
      const uint32_t* ybr = yb + ((c - 1) & 1) * YBUF;
      int lane = tid - 256;
      int tc = lane & 15, q = lane >> 4;
      const uint32_t* yrow = ybr + tc * YPAD + q * 8;
      floatx4 acc0a = {0,0,0,0}, acc0b = {0,0,0,0};
      floatx4 acc1a = {0,0,0,0}, acc1b = {0,0,0,0};
#pragma unroll
      for (int ks = 0; ks < 8; ++ks) {
        uint4 p0 = *(const uint4*)(yrow + ks * 32);
        uint4 p1 = *(const uint4*)(yrow + ks * 32 + 4);
        FragU ah, al;
        ah.u[0] = (p0.x & 0xFFFFu) | (p0.y << 16);
        ah.u[1] = (p0.z & 0xFFFFu) | (p0.w << 16);
        ah.u[2] = (p1.x & 0xFFFFu) | (p1.y << 16);
        ah.u[3] = (p1.z & 0xFFFFu) | (p1.w << 16);
        al.u[0] = (p0.x >> 16) | (p0.y & 0xFFFF0000u);
        al.u[1] = (p0.z >> 16) | (p0.w & 0xFFFF0000u);
        al.u[2] = (p1.x >> 16) | (p1.y & 0xFFFF0000u);
        al.u[3] = (p1.z >> 16) | (p1.w & 0xFFFF0000u);
        bf16x8 bh0 = *(const bf16x8*)&wf[(ks * 2 + 0) * 512 + lane * 8];
        bf16x8 bh1 = *(const bf16x8*)&wf[(ks * 2 + 1) * 512 + lane * 8];
        if (ks & 1) {
          acc0b = __builtin_amdgcn_mfma_f32_16x16x32_bf16(ah.s, bh0, acc0b, 0, 0, 0);
          acc0b = __builtin_amdgcn_mfma_f32_16x16x32_bf16(al.s, bh0, acc0b, 0, 0, 0);
          acc1b = __builtin_amdgcn_mfma_f32_16x16x32_bf16(ah.s, bh1, acc1b, 0, 0, 0);
          acc1b = __builtin_amdgcn_mfma_f32_16x16x32_bf16(al.s, bh1, acc1b, 0, 0, 0);
        } else {
          acc0a = __builtin_amdgcn_mfma_f32_16x16x32_bf16(ah.s, bh0, acc0a, 0, 0, 0);
          acc0a = __builtin_amdgcn_mfma_f32_16x16x32_bf16(al.s, bh0, acc0a, 0, 0, 0);
          acc1a = __builtin_amdgcn_mfma_f32_16x16x32_bf16(ah.s, bh1, acc1a, 0, 0, 0);
          acc1a = __builtin_amdgcn_mfma_f32_16x16x32_bf16(al.s, bh1, acc1a, 0, 0, 0);
        }
      }
      int t0 = (c - 1) * 16;
      floatx4 r0 = acc0a + acc0b;
      floatx4 r1 = acc1a + acc1b;
      // D layout: col = lane&15 (=o within tile), row = q*4 + reg (=t_local)
      *(floatx4*)&zout[tc * 256 + t0 + q * 4] = r0;
      *(floatx4*)&zout[(16 + tc) * 256 + t0 + q * 4] = r1;
    }
    __syncthreads();
  }
}

// ---------------------------------------------------------------------------
// CB: combine 4 K-quarters + direct-channel term + bias + activation.
// ---------------------------------------------------------------------------
__global__ __launch_bounds__(256) void cb_kernel(
    const float* __restrict__ a1, const float* __restrict__ S2eff,
    const float* __restrict__ zpart, float* __restrict__ out) {
  int nb = blockIdx.x;
  int n = nb >> 5;
  int t = threadIdx.x;
  __shared__ float xs[32][256];
  const float* a1nb = a1 + (size_t)nb * 8192;
  for (int c = 0; c < 32; ++c) xs[c][t] = a1nb[c * 256 + t];
  __syncthreads();
  const float* S2n = S2eff + (size_t)n * 1057 * 32;
  const float* zp = zpart + (size_t)nb * 4 * 8192;
  float* op = out + (size_t)nb * 8192;
  for (int o = 0; o < 32; ++o) {
    float z = S2n[1056 * 32 + o];
#pragma unroll
    for (int c = 0; c < 32; ++c) z += xs[c][t] * S2n[(c * 33) * 32 + o];
    z += zp[o * 256 + t] + zp[8192 + o * 256 + t] +
         zp[16384 + o * 256 + t] + zp[24576 + o * 256 + t];
    op[o * 256 + t] = 0.05f + 0.5f * tanhf((z - 0.3f) * 3.0f);
  }
}

// ---------------------------------------------------------------------------
// Launch
// ---------------------------------------------------------------------------
struct KeyPair { uint32_t a, b; };

// jax.random.split(key, 4), PARTITIONABLE (foldlike): key_i = threefry(key,(0,i))
static inline void split4_host(KeyPair key, KeyPair out[4]) {
  for (uint32_t i = 0; i < 4; ++i) {
    uint32_t x0 = 0u, x1 = i;
    tf2x32(key.a, key.b, x0, x1);
    out[i] = {x0, x1};
  }
}

extern "C" void kernel_launch(void* const* d_in, const int* in_sizes, int n_in,
                              void* d_out, int out_size, void* d_ws, size_t ws_size,
                              hipStream_t stream) {
  const float* x   = (const float*)d_in[0];   // (4,32,32,256)
  const float* th1 = (const float*)d_in[1];   // (34,32)
  const float* th2 = (const float*)d_in[2];   // (1058,32)
  const float* Rlf = (const float*)d_in[3];   // (32,32,2)
  const float* Clf = (const float*)d_in[4];   // (32,32,2)
  float* out = (float*)d_out;                 // (4,32,32,256)
  float* ws = (float*)d_ws;

  // workspace layout (floats)
  float* S1    = ws;                  // 4224
  float* den2p = ws + 4224;           // 1024 (4 n x 8 partials x 32 o)
  float* S2    = ws + 5248;           // 135296
  float* a1    = ws + 140544;         // 1048576
  float* be1   = ws + 1189120;        // 1048576
  float* be2   = ws + 2237696;        // 1048576
  float* zpart = ws + 3286272;        // 4194304 (512 blocks x 8192) ~29.9 MB total

  KeyPair root{0u, 42u};
  KeyPair kk[4];  split4_host(root, kk);     // {k1, k2, k3, k4}
  KeyPair f1[4];  split4_host(kk[1], f1);    // {kR1, kC1, kmu1, k01}
  KeyPair f2[4];  split4_host(kk[2], f2);    // {kR2, kC2, kmu2, k02}

  prep0_kernel<<<dim3(1060), dim3(256), 0, stream>>>(
      Rlf, Clf, th1, th2, be1, be2, S1, den2p,
      kk[0].a, kk[0].b, kk[3].a, kk[3].b,
      f1[0].a, f1[0].b, f1[1].a, f1[1].b, f1[2].a, f1[2].b,
      f2[0].a, f2[0].b, f2[1].a, f2[1].b, f2[2].a, f2[2].b);
  prep1_kernel<<<dim3(657), dim3(256), 0, stream>>>(
      th2, den2p, S2, x, S1, a1, kk[3].a, kk[3].b);
  fk3_kernel<<<dim3(512), dim3(320), 0, stream>>>(
      a1, S2, be1, be2, zpart, f1[3].a, f1[3].b, f2[3].a, f2[3].b);
  cb_kernel<<<dim3(128), dim3(256), 0, stream>>>(a1, S2, zpart, out);
}